// Round 1
// baseline (747.580 us; speedup 1.0000x reference)
//
#include <hip/hip_runtime.h>
#include <hip/hip_bf16.h>

// Problem constants
#define B_    16
#define C_    128
#define TWOC  256
#define OUT_  128
#define HW    16384   // 128*128
#define WDIM  128
#define HDIM  128
#define KTOT  1152    // C_*9

typedef __attribute__((ext_vector_type(8))) short short8;   // 8 bf16 (4 VGPRs)
typedef __attribute__((ext_vector_type(4))) float floatx4;  // 4 fp32 acc

__device__ __forceinline__ ushort f2bf(float f) {
    union { float f; uint u; } x; x.f = f;
    uint r = (x.u + 0x7FFFu + ((x.u >> 16) & 1u)) >> 16;   // RNE
    return (ushort)r;
}

// ---------------------------------------------------------------------------
// Kernel 1: global average pool over H,W of concat([ir,vi]) -> pooled[B][256]
// ---------------------------------------------------------------------------
__global__ __launch_bounds__(256) void pool_kernel(
    const float* __restrict__ ir, const float* __restrict__ vi,
    float* __restrict__ pooled)
{
    int c2 = blockIdx.x;          // 0..255
    int b  = blockIdx.y;          // 0..15
    const float* src = (c2 < C_) ? (ir + ((size_t)b * C_ + c2) * HW)
                                 : (vi + ((size_t)b * C_ + (c2 - C_)) * HW);
    const float4* s4 = (const float4*)src;
    float s = 0.f;
    for (int i = threadIdx.x; i < HW / 4; i += 256) {
        float4 v = s4[i];
        s += (v.x + v.y) + (v.z + v.w);
    }
    #pragma unroll
    for (int off = 32; off; off >>= 1) s += __shfl_down(s, off);
    __shared__ float ps[4];
    if ((threadIdx.x & 63) == 0) ps[threadIdx.x >> 6] = s;
    __syncthreads();
    if (threadIdx.x == 0)
        pooled[b * TWOC + c2] = (ps[0] + ps[1] + ps[2] + ps[3]) * (1.0f / (float)HW);
}

// ---------------------------------------------------------------------------
// Kernel 2: tiny MLPs: hk = relu(pooled@kg_w1^T+b1), hb = relu(pooled@bg_w1^T+b1),
//           dyn_b = hb@bg_w2^T + bg_b2
// ---------------------------------------------------------------------------
__global__ __launch_bounds__(256) void gen_small_kernel(
    const float* __restrict__ pooled,
    const float* __restrict__ kg_w1, const float* __restrict__ kg_b1,
    const float* __restrict__ bg_w1, const float* __restrict__ bg_b1,
    const float* __restrict__ bg_w2, const float* __restrict__ bg_b2,
    float* __restrict__ hk, float* __restrict__ dyn_b)
{
    __shared__ float pool_s[B_][TWOC];
    __shared__ float hb_s[B_][32];
    int t = threadIdx.x;
    for (int i = t; i < B_ * TWOC; i += 256) pool_s[i >> 8][i & 255] = pooled[i];
    __syncthreads();
    // hk: 16*64
    for (int idx = t; idx < B_ * 64; idx += 256) {
        int b = idx >> 6, j = idx & 63;
        float s = kg_b1[j];
        const float* w = kg_w1 + j * TWOC;
        #pragma unroll 8
        for (int k2 = 0; k2 < TWOC; ++k2) s += pool_s[b][k2] * w[k2];
        hk[idx] = fmaxf(s, 0.f);
    }
    // hb: 16*32
    for (int idx = t; idx < B_ * 32; idx += 256) {
        int b = idx >> 5, j = idx & 31;
        float s = bg_b1[j];
        const float* w = bg_w1 + j * TWOC;
        #pragma unroll 8
        for (int k2 = 0; k2 < TWOC; ++k2) s += pool_s[b][k2] * w[k2];
        hb_s[b][j] = fmaxf(s, 0.f);
    }
    __syncthreads();
    // dyn_b: 16*128
    for (int idx = t; idx < B_ * OUT_; idx += 256) {
        int b = idx >> 7, o = idx & 127;
        float s = bg_b2[o];
        const float* w = bg_w2 + o * 32;
        #pragma unroll
        for (int k2 = 0; k2 < 32; ++k2) s += hb_s[b][k2] * w[k2];
        dyn_b[idx] = s;
    }
}

// ---------------------------------------------------------------------------
// Kernel 3: dynamic kernel generation -> bf16, conv-friendly layout
//   dynk[b][o][kk=(kh*3+kw)][c]  (k-dim contiguous per (kh,kw): c fastest)
//   source row r of kg_w2 = o*1152 + c*9 + kk   (orig layout [o][c][kh][kw])
// ---------------------------------------------------------------------------
__global__ __launch_bounds__(256) void gen_dynk_kernel(
    const float* __restrict__ kg_w2, const float* __restrict__ kg_b2,
    const float* __restrict__ hk, ushort* __restrict__ dynk)
{
    __shared__ float hk_s[B_][64];
    int t = threadIdx.x;
    for (int i = t; i < B_ * 64; i += 256) hk_s[i >> 6][i & 63] = hk[i];
    __syncthreads();

    int i = blockIdx.x * 256 + t;            // dest index in [0,147456)
    int o = i / KTOT;
    int rem = i - o * KTOT;
    int r = o * KTOT + (rem & 127) * 9 + (rem >> 7);   // source row

    float wrow[64];
    const float4* w4 = (const float4*)(kg_w2 + (size_t)r * 64);
    #pragma unroll
    for (int q = 0; q < 16; ++q) {
        float4 v = w4[q];
        wrow[4 * q + 0] = v.x; wrow[4 * q + 1] = v.y;
        wrow[4 * q + 2] = v.z; wrow[4 * q + 3] = v.w;
    }
    float bias = kg_b2[r];
    #pragma unroll
    for (int b = 0; b < B_; ++b) {
        float s = bias;
        #pragma unroll
        for (int k2 = 0; k2 < 64; ++k2) s += hk_s[b][k2] * wrow[k2];
        dynk[(size_t)(b * OUT_ + o) * KTOT + rem] = f2bf(s);
    }
}

// ---------------------------------------------------------------------------
// Kernel 4: enhance = relu(BN(concat @ en_w^T)) -> enh bf16, NHWC layout
//   GEMM per b: D[c_out=128][pixels], K=256. Block: 128 c_out x 128 px (one row)
// ---------------------------------------------------------------------------
__global__ __launch_bounds__(256) void enhance_kernel(
    const float* __restrict__ ir, const float* __restrict__ vi,
    const float* __restrict__ en_w,
    const float* __restrict__ gamma, const float* __restrict__ beta,
    const float* __restrict__ mean, const float* __restrict__ var,
    ushort* __restrict__ enh)
{
    __shared__ ushort Xs[128][32];   // [pixel][c2 within chunk], bf16
    int b = blockIdx.y;
    int p0 = blockIdx.x * 128;       // one image row of pixels
    int t = threadIdx.x;
    int lane = t & 63, wave = t >> 6;
    int wr = wave >> 1, wc = wave & 1;
    int lr = lane & 15, kg = lane >> 4;
    int px = t & 127, half = t >> 7;

    floatx4 acc[4][4] = {};

    for (int kc = 0; kc < 8; ++kc) {
        // --- stage: 32 c2-rows x 128 px, transposed to [px][c2] bf16 ---
        int c2b = kc * 32 + half * 16;
        const float* src = (c2b < C_) ? (ir + ((size_t)b * C_ + c2b) * HW + p0 + px)
                                      : (vi + ((size_t)b * C_ + (c2b - C_)) * HW + p0 + px);
        uint u[8];
        #pragma unroll
        for (int jj = 0; jj < 8; ++jj) {
            float f0 = src[(size_t)(2 * jj) * HW];
            float f1 = src[(size_t)(2 * jj + 1) * HW];
            u[jj] = (uint)f2bf(f0) | ((uint)f2bf(f1) << 16);
        }
        __syncthreads();   // previous iter's Xs reads done
        uint4* dst = (uint4*)&Xs[px][half * 16];
        dst[0] = make_uint4(u[0], u[1], u[2], u[3]);
        dst[1] = make_uint4(u[4], u[5], u[6], u[7]);
        __syncthreads();

        // --- fragments + MFMA ---
        short8 af[4], bfr[4];
        #pragma unroll
        for (int i2 = 0; i2 < 4; ++i2) {
            int co = wr * 64 + i2 * 16 + lr;
            const float* wp = en_w + (size_t)co * TWOC + kc * 32 + kg * 8;
            float4 w0 = *(const float4*)wp;
            float4 w1 = *(const float4*)(wp + 4);
            short8 a;
            a[0] = (short)f2bf(w0.x); a[1] = (short)f2bf(w0.y);
            a[2] = (short)f2bf(w0.z); a[3] = (short)f2bf(w0.w);
            a[4] = (short)f2bf(w1.x); a[5] = (short)f2bf(w1.y);
            a[6] = (short)f2bf(w1.z); a[7] = (short)f2bf(w1.w);
            af[i2] = a;
        }
        #pragma unroll
        for (int j = 0; j < 4; ++j) {
            int pl = wc * 64 + j * 16 + lr;
            bfr[j] = *(const short8*)&Xs[pl][kg * 8];
        }
        #pragma unroll
        for (int i2 = 0; i2 < 4; ++i2)
            #pragma unroll
            for (int j = 0; j < 4; ++j)
                acc[i2][j] = __builtin_amdgcn_mfma_f32_16x16x32_bf16(af[i2], bfr[j], acc[i2][j], 0, 0, 0);
    }

    // --- epilogue: BN + ReLU, store NHWC bf16 ---
    #pragma unroll
    for (int i2 = 0; i2 < 4; ++i2) {
        int co_b = wr * 64 + i2 * 16 + kg * 4;   // 4 consecutive c_out
        float4 g  = *(const float4*)&gamma[co_b];
        float4 vv = *(const float4*)&var[co_b];
        float4 bt = *(const float4*)&beta[co_b];
        float4 mn = *(const float4*)&mean[co_b];
        float inv0 = g.x * rsqrtf(vv.x + 1e-5f), inv1 = g.y * rsqrtf(vv.y + 1e-5f);
        float inv2 = g.z * rsqrtf(vv.z + 1e-5f), inv3 = g.w * rsqrtf(vv.w + 1e-5f);
        float ad0 = bt.x - mn.x * inv0, ad1 = bt.y - mn.y * inv1;
        float ad2 = bt.z - mn.z * inv2, ad3 = bt.w - mn.w * inv3;
        #pragma unroll
        for (int j = 0; j < 4; ++j) {
            int pl = wc * 64 + j * 16 + lr;
            float v0 = fmaxf(acc[i2][j][0] * inv0 + ad0, 0.f);
            float v1 = fmaxf(acc[i2][j][1] * inv1 + ad1, 0.f);
            float v2 = fmaxf(acc[i2][j][2] * inv2 + ad2, 0.f);
            float v3 = fmaxf(acc[i2][j][3] * inv3 + ad3, 0.f);
            uint2 pk;
            pk.x = (uint)f2bf(v0) | ((uint)f2bf(v1) << 16);
            pk.y = (uint)f2bf(v2) | ((uint)f2bf(v3) << 16);
            *(uint2*)&enh[((size_t)b * HW + p0 + pl) * C_ + co_b] = pk;
        }
    }
}

// ---------------------------------------------------------------------------
// Kernel 5: per-sample dynamic 3x3 conv (implicit GEMM), + dyn_b, out NCHW f32
//   Block tile: 128 o x 128 pixels (8 rows x 16 cols). LDS: 10x18 halo x 32c.
// ---------------------------------------------------------------------------
__global__ __launch_bounds__(256) void dynconv_kernel(
    const ushort* __restrict__ enh, const ushort* __restrict__ dynk,
    const float* __restrict__ dyn_b, float* __restrict__ out)
{
    __shared__ ushort halo[180][32];   // [hy*18+hx][c], 11.25 KB
    int b  = blockIdx.z;
    int gy0 = blockIdx.y * 8;
    int gx0 = blockIdx.x * 16;
    int t = threadIdx.x, lane = t & 63, wave = t >> 6;
    int wr = wave >> 1, wc = wave & 1;
    int lr = lane & 15, kg = lane >> 4;

    floatx4 acc[4][4] = {};

    for (int kc = 0; kc < 4; ++kc) {
        // --- stage halo tile: 180 px * 32 c bf16 = 720 x 16B segments ---
        uint4 st[3];
        #pragma unroll
        for (int s = 0; s < 3; ++s) {
            int seg = t + s * 256;
            int hp = seg >> 2, coff = (seg & 3) * 8;
            uint4 v = make_uint4(0, 0, 0, 0);
            if (hp < 180) {
                int hy = hp / 18;
                int hx = hp - hy * 18;
                int gy = gy0 - 1 + hy, gx = gx0 - 1 + hx;
                if (gy >= 0 && gy < HDIM && gx >= 0 && gx < WDIM)
                    v = *(const uint4*)&enh[((size_t)b * HW + gy * WDIM + gx) * C_ + kc * 32 + coff];
            }
            st[s] = v;
        }
        __syncthreads();   // previous iter's halo reads done
        #pragma unroll
        for (int s = 0; s < 3; ++s) {
            int seg = t + s * 256;
            int hp = seg >> 2, coff = (seg & 3) * 8;
            if (hp < 180) *(uint4*)&halo[hp][coff] = st[s];
        }
        __syncthreads();

        // --- 9 MFMA k-steps over (kh,kw), K=32 c each ---
        #pragma unroll
        for (int kh = 0; kh < 3; ++kh) {
            #pragma unroll
            for (int kw = 0; kw < 3; ++kw) {
                int kkid = kh * 3 + kw;
                short8 af[4], bfr[4];
                #pragma unroll
                for (int i2 = 0; i2 < 4; ++i2) {
                    int o = wr * 64 + i2 * 16 + lr;
                    af[i2] = *(const short8*)&dynk[(size_t)(b * OUT_ + o) * KTOT + kkid * C_ + kc * 32 + kg * 8];
                }
                #pragma unroll
                for (int j = 0; j < 4; ++j) {
                    int p = wc * 64 + j * 16 + lr;
                    int py = p >> 4, px = p & 15;
                    bfr[j] = *(const short8*)&halo[(py + kh) * 18 + (px + kw)][kg * 8];
                }
                #pragma unroll
                for (int i2 = 0; i2 < 4; ++i2)
                    #pragma unroll
                    for (int j = 0; j < 4; ++j)
                        acc[i2][j] = __builtin_amdgcn_mfma_f32_16x16x32_bf16(af[i2], bfr[j], acc[i2][j], 0, 0, 0);
            }
        }
    }

    // --- epilogue: + dyn_b, store NCHW fp32 ---
    #pragma unroll
    for (int i2 = 0; i2 < 4; ++i2) {
        int o_b = wr * 64 + i2 * 16 + kg * 4;   // 4 consecutive o
        float4 db = *(const float4*)&dyn_b[b * OUT_ + o_b];
        float dbv[4] = {db.x, db.y, db.z, db.w};
        #pragma unroll
        for (int j = 0; j < 4; ++j) {
            int p = wc * 64 + j * 16 + lr;
            int py = p >> 4, px = p & 15;
            int gy = gy0 + py, gx = gx0 + px;
            #pragma unroll
            for (int r = 0; r < 4; ++r) {
                int o = o_b + r;
                out[((size_t)(b * OUT_ + o)) * HW + gy * WDIM + gx] = acc[i2][j][r] + dbv[r];
            }
        }
    }
}

// ---------------------------------------------------------------------------
extern "C" void kernel_launch(void* const* d_in, const int* in_sizes, int n_in,
                              void* d_out, int out_size, void* d_ws, size_t ws_size,
                              hipStream_t stream)
{
    const float* ir    = (const float*)d_in[0];
    const float* vi    = (const float*)d_in[1];
    const float* kg_w1 = (const float*)d_in[2];
    const float* kg_b1 = (const float*)d_in[3];
    const float* kg_w2 = (const float*)d_in[4];
    const float* kg_b2 = (const float*)d_in[5];
    const float* bg_w1 = (const float*)d_in[6];
    const float* bg_b1 = (const float*)d_in[7];
    const float* bg_w2 = (const float*)d_in[8];
    const float* bg_b2 = (const float*)d_in[9];
    const float* en_w  = (const float*)d_in[10];
    const float* bn_g  = (const float*)d_in[11];
    const float* bn_b  = (const float*)d_in[12];
    const float* bn_m  = (const float*)d_in[13];
    const float* bn_v  = (const float*)d_in[14];
    float* out = (float*)d_out;

    // workspace layout
    char* ws = (char*)d_ws;
    float*  pooled = (float*)(ws + 0);                    // 16*256*4   = 16384
    float*  dyn_b  = (float*)(ws + 16384);                // 16*128*4   = 8192
    float*  hk     = (float*)(ws + 24576);                // 16*64*4    = 4096
    ushort* dynk   = (ushort*)(ws + 32768);               // 16*128*1152*2 = 4718592
    ushort* enh    = (ushort*)(ws + 32768 + 4718592);     // 16*16384*128*2 = 67108864

    pool_kernel<<<dim3(TWOC, B_), 256, 0, stream>>>(ir, vi, pooled);
    gen_small_kernel<<<1, 256, 0, stream>>>(pooled, kg_w1, kg_b1, bg_w1, bg_b1,
                                            bg_w2, bg_b2, hk, dyn_b);
    gen_dynk_kernel<<<576, 256, 0, stream>>>(kg_w2, kg_b2, hk, dynk);
    enhance_kernel<<<dim3(HDIM, B_), 256, 0, stream>>>(ir, vi, en_w, bn_g, bn_b,
                                                       bn_m, bn_v, enh);
    dynconv_kernel<<<dim3(WDIM / 16, HDIM / 8, B_), 256, 0, stream>>>(enh, dynk, dyn_b, out);
}

// Round 2
// 692.240 us; speedup vs baseline: 1.0799x; 1.0799x over previous
//
#include <hip/hip_runtime.h>
#include <hip/hip_bf16.h>

#define B_    16
#define C_    128
#define TWOC  256
#define OUT_  128
#define HW    16384
#define WDIM  128
#define HDIM  128
#define KTOT  1152

typedef __attribute__((ext_vector_type(8))) short short8;
typedef __attribute__((ext_vector_type(4))) float floatx4;

__device__ __forceinline__ ushort f2bf(float f) {
    union { float f; uint u; } x; x.f = f;
    uint r = (x.u + 0x7FFFu + ((x.u >> 16) & 1u)) >> 16;   // RNE
    return (ushort)r;
}
__device__ __forceinline__ float bf2f(ushort u) {
    union { float f; uint u; } x; x.u = ((uint)u) << 16;
    return x.f;
}

// ---------------------------------------------------------------------------
// zero pooled accumulator (16*256 floats)
// ---------------------------------------------------------------------------
__global__ __launch_bounds__(256) void zero_pooled_kernel(float* __restrict__ p) {
    int i = blockIdx.x * 256 + threadIdx.x;
    if (i < B_ * TWOC) p[i] = 0.f;
}

// ---------------------------------------------------------------------------
// Kernel 1 (fused): enhance = relu(BN(concat @ en_w^T)) -> enh bf16 NHWC
//                   + global-average-pool partial sums -> atomicAdd(pooled)
//   Per block: one image row (128 px) of one b. K=256 in 8 chunks of 32.
// ---------------------------------------------------------------------------
__global__ __launch_bounds__(256) void enhance_kernel(
    const float* __restrict__ ir, const float* __restrict__ vi,
    const float* __restrict__ en_w,
    const float* __restrict__ gamma, const float* __restrict__ beta,
    const float* __restrict__ mean, const float* __restrict__ var,
    ushort* __restrict__ enh, float* __restrict__ pooled)
{
    __shared__ ushort Xs[128][40];   // pad 32->40 shorts: conflict-free b128 phases
    __shared__ float red[256];
    int b = blockIdx.y;
    int p0 = blockIdx.x * 128;
    int t = threadIdx.x;
    int lane = t & 63, wave = t >> 6;
    int wr = wave >> 1, wc = wave & 1;
    int lr = lane & 15, kg = lane >> 4;
    int px = t & 127, half = t >> 7;

    floatx4 acc[4][4] = {};
    float pp[8];

    #pragma unroll
    for (int kc = 0; kc < 8; ++kc) {
        int c2b = kc * 32 + half * 16;
        const float* src = (c2b < C_) ? (ir + ((size_t)b * C_ + c2b) * HW + p0 + px)
                                      : (vi + ((size_t)b * C_ + (c2b - C_)) * HW + p0 + px);
        uint u[8];
        #pragma unroll
        for (int jj = 0; jj < 8; ++jj) {
            float f0 = src[(size_t)(2 * jj) * HW];
            float f1 = src[(size_t)(2 * jj + 1) * HW];
            u[jj] = (uint)f2bf(f0) | ((uint)f2bf(f1) << 16);
        }
        __syncthreads();
        uint4* dst = (uint4*)&Xs[px][half * 16];
        dst[0] = make_uint4(u[0], u[1], u[2], u[3]);
        dst[1] = make_uint4(u[4], u[5], u[6], u[7]);
        __syncthreads();

        short8 af[4], bfr[4];
        #pragma unroll
        for (int i2 = 0; i2 < 4; ++i2) {
            int co = wr * 64 + i2 * 16 + lr;
            const float* wp = en_w + (size_t)co * TWOC + kc * 32 + kg * 8;
            float4 w0 = *(const float4*)wp;
            float4 w1 = *(const float4*)(wp + 4);
            short8 a;
            a[0] = (short)f2bf(w0.x); a[1] = (short)f2bf(w0.y);
            a[2] = (short)f2bf(w0.z); a[3] = (short)f2bf(w0.w);
            a[4] = (short)f2bf(w1.x); a[5] = (short)f2bf(w1.y);
            a[6] = (short)f2bf(w1.z); a[7] = (short)f2bf(w1.w);
            af[i2] = a;
        }
        #pragma unroll
        for (int j = 0; j < 4; ++j) {
            int pl = wc * 64 + j * 16 + lr;
            bfr[j] = *(const short8*)&Xs[pl][kg * 8];
        }
        #pragma unroll
        for (int i2 = 0; i2 < 4; ++i2)
            #pragma unroll
            for (int j = 0; j < 4; ++j)
                acc[i2][j] = __builtin_amdgcn_mfma_f32_16x16x32_bf16(af[i2], bfr[j], acc[i2][j], 0, 0, 0);

        // pool partial: thread t sums channel (kc*32 + (t&31)) over 16 pixels
        {
            int c = t & 31, grp = t >> 5;
            float s = 0.f;
            #pragma unroll
            for (int q = 0; q < 16; ++q) s += bf2f(Xs[grp * 16 + q][c]);
            pp[kc] = s;
        }
    }

    // epilogue: BN + ReLU, store NHWC bf16
    #pragma unroll
    for (int i2 = 0; i2 < 4; ++i2) {
        int co_b = wr * 64 + i2 * 16 + kg * 4;
        float4 g  = *(const float4*)&gamma[co_b];
        float4 vv = *(const float4*)&var[co_b];
        float4 bt = *(const float4*)&beta[co_b];
        float4 mn = *(const float4*)&mean[co_b];
        float inv0 = g.x * rsqrtf(vv.x + 1e-5f), inv1 = g.y * rsqrtf(vv.y + 1e-5f);
        float inv2 = g.z * rsqrtf(vv.z + 1e-5f), inv3 = g.w * rsqrtf(vv.w + 1e-5f);
        float ad0 = bt.x - mn.x * inv0, ad1 = bt.y - mn.y * inv1;
        float ad2 = bt.z - mn.z * inv2, ad3 = bt.w - mn.w * inv3;
        #pragma unroll
        for (int j = 0; j < 4; ++j) {
            int pl = wc * 64 + j * 16 + lr;
            float v0 = fmaxf(acc[i2][j][0] * inv0 + ad0, 0.f);
            float v1 = fmaxf(acc[i2][j][1] * inv1 + ad1, 0.f);
            float v2 = fmaxf(acc[i2][j][2] * inv2 + ad2, 0.f);
            float v3 = fmaxf(acc[i2][j][3] * inv3 + ad3, 0.f);
            uint2 pk;
            pk.x = (uint)f2bf(v0) | ((uint)f2bf(v1) << 16);
            pk.y = (uint)f2bf(v2) | ((uint)f2bf(v3) << 16);
            *(uint2*)&enh[((size_t)b * HW + p0 + pl) * C_ + co_b] = pk;
        }
    }

    // pool finalize: reduce 8 groups -> 1 atomic per channel chunk
    #pragma unroll
    for (int kc = 0; kc < 8; ++kc) {
        __syncthreads();
        red[t] = pp[kc];
        __syncthreads();
        if (t < 32) {
            float s = red[t] + red[32 + t] + red[64 + t] + red[96 + t]
                    + red[128 + t] + red[160 + t] + red[192 + t] + red[224 + t];
            atomicAdd(&pooled[b * TWOC + kc * 32 + t], s);
        }
    }
}

// ---------------------------------------------------------------------------
// Kernel 2: parallel first-layer MLPs. pooled holds RAW sums (scale by 1/HW).
//   outputs: hk[16][64], hb[16][32]
// ---------------------------------------------------------------------------
__global__ __launch_bounds__(256) void gen_mlp1_kernel(
    const float* __restrict__ pooled,
    const float* __restrict__ kg_w1, const float* __restrict__ kg_b1,
    const float* __restrict__ bg_w1, const float* __restrict__ bg_b1,
    float* __restrict__ hk, float* __restrict__ hb)
{
    const float scale = 1.0f / (float)HW;
    int idx = blockIdx.x * 256 + threadIdx.x;   // 0..1535
    if (idx < B_ * 64) {
        int b = idx >> 6, j = idx & 63;
        const float4* w = (const float4*)(kg_w1 + (size_t)j * TWOC);
        const float4* p = (const float4*)(pooled + b * TWOC);
        float s = 0.f;
        #pragma unroll 8
        for (int q = 0; q < 64; ++q) {
            float4 wv = w[q], pv = p[q];
            s += (wv.x * pv.x + wv.y * pv.y) + (wv.z * pv.z + wv.w * pv.w);
        }
        hk[idx] = fmaxf(kg_b1[j] + s * scale, 0.f);
    } else if (idx < B_ * 64 + B_ * 32) {
        int e = idx - B_ * 64;
        int b = e >> 5, j = e & 31;
        const float4* w = (const float4*)(bg_w1 + (size_t)j * TWOC);
        const float4* p = (const float4*)(pooled + b * TWOC);
        float s = 0.f;
        #pragma unroll 8
        for (int q = 0; q < 64; ++q) {
            float4 wv = w[q], pv = p[q];
            s += (wv.x * pv.x + wv.y * pv.y) + (wv.z * pv.z + wv.w * pv.w);
        }
        hb[e] = fmaxf(bg_b1[j] + s * scale, 0.f);
    }
}

// ---------------------------------------------------------------------------
// Kernel 3: dynamic kernel gen -> dynk[b][kk][o][c] bf16 ; block 0: dyn_b
// ---------------------------------------------------------------------------
__global__ __launch_bounds__(256) void gen_dynk_kernel(
    const float* __restrict__ kg_w2, const float* __restrict__ kg_b2,
    const float* __restrict__ hk, const float* __restrict__ hb,
    const float* __restrict__ bg_w2, const float* __restrict__ bg_b2,
    ushort* __restrict__ dynk, float* __restrict__ dyn_b)
{
    __shared__ float hk_s[B_][64];
    int t = threadIdx.x;
    for (int i = t; i < B_ * 64; i += 256) hk_s[i >> 6][i & 63] = hk[i];
    __syncthreads();

    int i = blockIdx.x * 256 + t;     // dest-linear, 0..147455
    int kk = i >> 14;                 // 9 << 14 == 147456
    int o  = (i >> 7) & 127;
    int c  = i & 127;
    int r  = o * KTOT + c * 9 + kk;   // source row of kg_w2

    float wrow[64];
    const float4* w4 = (const float4*)(kg_w2 + (size_t)r * 64);
    #pragma unroll
    for (int q = 0; q < 16; ++q) {
        float4 v = w4[q];
        wrow[4 * q + 0] = v.x; wrow[4 * q + 1] = v.y;
        wrow[4 * q + 2] = v.z; wrow[4 * q + 3] = v.w;
    }
    float bias = kg_b2[r];
    #pragma unroll
    for (int b = 0; b < B_; ++b) {
        float s = bias;
        #pragma unroll
        for (int k2 = 0; k2 < 64; ++k2) s += hk_s[b][k2] * wrow[k2];
        dynk[((size_t)(b * 9 + kk) * 128 + o) * 128 + c] = f2bf(s);
    }

    if (blockIdx.x == 0) {
        for (int e = t; e < B_ * OUT_; e += 256) {
            int b = e >> 7, o2 = e & 127;
            float s = bg_b2[o2];
            const float* w = bg_w2 + o2 * 32;
            const float* h = hb + b * 32;
            #pragma unroll
            for (int k2 = 0; k2 < 32; ++k2) s += h[k2] * w[k2];
            dyn_b[e] = s;
        }
    }
}

// ---------------------------------------------------------------------------
// Kernel 4: dynamic 3x3 conv, implicit GEMM. Tile: 128 o x (8x16) px.
//   A-frags (dynk) register-prefetched one kk ahead; kk loop is barrier-free.
//   halo: 64-channel chunks, rows padded to 72 shorts (conflict-free phases).
// ---------------------------------------------------------------------------
__global__ __launch_bounds__(256, 3) void dynconv_kernel(
    const ushort* __restrict__ enh, const ushort* __restrict__ dynk,
    const float* __restrict__ dyn_b, float* __restrict__ out)
{
    __shared__ ushort halo[180][72];   // 10x18 px halo, 64c, pad 8 -> 25.9 KB
    const int b = blockIdx.z;
    const int gy0 = blockIdx.y * 8, gx0 = blockIdx.x * 16;
    const int t = threadIdx.x, lane = t & 63, wave = t >> 6;
    const int wr = wave >> 1, wc = wave & 1;
    const int lr = lane & 15, kg = lane >> 4;
    const ushort* dynk_b = dynk + (size_t)b * 9 * 128 * 128;
    const ushort* enh_b  = enh + (size_t)b * HW * C_;

    floatx4 acc[4][4] = {};
    short8 a_cur[8], a_nxt[8];

    for (int h = 0; h < 2; ++h) {
        // --- load halo regs (180 px x 64 c bf16 = 1440 16B segs, 6 passes) ---
        uint4 hreg[6];
        #pragma unroll
        for (int s = 0; s < 6; ++s) {
            int seg = s * 256 + t;
            int hp = seg >> 3, c8 = seg & 7;
            uint4 v = make_uint4(0, 0, 0, 0);
            if (hp < 180) {
                int hy = hp / 18, hx = hp - hy * 18;
                int gy = gy0 - 1 + hy, gx = gx0 - 1 + hx;
                if ((unsigned)gy < 128u && (unsigned)gx < 128u)
                    v = *(const uint4*)&enh_b[((size_t)(gy * WDIM + gx)) * C_ + h * 64 + c8 * 8];
            }
            hreg[s] = v;
        }
        // --- prefetch A for kk=0 (q = ks*4 + i2) ---
        #pragma unroll
        for (int q = 0; q < 8; ++q) {
            int ks = q >> 2, i2 = q & 3;
            int o = wr * 64 + i2 * 16 + lr;
            a_cur[q] = *(const short8*)&dynk_b[(size_t)(0 * 128 + o) * 128 + h * 64 + ks * 32 + kg * 8];
        }
        __syncthreads();   // previous chunk's halo reads done
        #pragma unroll
        for (int s = 0; s < 6; ++s) {
            int seg = s * 256 + t;
            int hp = seg >> 3, c8 = seg & 7;
            if (hp < 180) *(uint4*)&halo[hp][c8 * 8] = hreg[s];
        }
        __syncthreads();   // halo ready; kk loop needs no further barriers

        #pragma unroll
        for (int kk = 0; kk < 9; ++kk) {
            if (kk < 8) {
                #pragma unroll
                for (int q = 0; q < 8; ++q) {
                    int ks = q >> 2, i2 = q & 3;
                    int o = wr * 64 + i2 * 16 + lr;
                    a_nxt[q] = *(const short8*)&dynk_b[(size_t)((kk + 1) * 128 + o) * 128 + h * 64 + ks * 32 + kg * 8];
                }
            }
            const int kh = kk / 3, kw = kk - kh * 3;
            #pragma unroll
            for (int ks = 0; ks < 2; ++ks) {
                short8 bfr[4];
                #pragma unroll
                for (int j = 0; j < 4; ++j) {
                    int p = wc * 64 + j * 16 + lr;
                    int py = p >> 4, px = p & 15;
                    bfr[j] = *(const short8*)&halo[(py + kh) * 18 + (px + kw)][ks * 32 + kg * 8];
                }
                #pragma unroll
                for (int i2 = 0; i2 < 4; ++i2)
                    #pragma unroll
                    for (int j = 0; j < 4; ++j)
                        acc[i2][j] = __builtin_amdgcn_mfma_f32_16x16x32_bf16(a_cur[ks * 4 + i2], bfr[j], acc[i2][j], 0, 0, 0);
            }
            #pragma unroll
            for (int q = 0; q < 8; ++q) a_cur[q] = a_nxt[q];
        }
    }

    // --- epilogue: + dyn_b, store NCHW fp32 ---
    #pragma unroll
    for (int i2 = 0; i2 < 4; ++i2) {
        int o_b = wr * 64 + i2 * 16 + kg * 4;
        float4 db = *(const float4*)&dyn_b[b * OUT_ + o_b];
        float dbv[4] = {db.x, db.y, db.z, db.w};
        #pragma unroll
        for (int j = 0; j < 4; ++j) {
            int p = wc * 64 + j * 16 + lr;
            int py = p >> 4, px = p & 15;
            int gy = gy0 + py, gx = gx0 + px;
            #pragma unroll
            for (int r = 0; r < 4; ++r) {
                int o = o_b + r;
                out[((size_t)(b * OUT_ + o)) * HW + gy * WDIM + gx] = acc[i2][j][r] + dbv[r];
            }
        }
    }
}

// ---------------------------------------------------------------------------
extern "C" void kernel_launch(void* const* d_in, const int* in_sizes, int n_in,
                              void* d_out, int out_size, void* d_ws, size_t ws_size,
                              hipStream_t stream)
{
    const float* ir    = (const float*)d_in[0];
    const float* vi    = (const float*)d_in[1];
    const float* kg_w1 = (const float*)d_in[2];
    const float* kg_b1 = (const float*)d_in[3];
    const float* kg_w2 = (const float*)d_in[4];
    const float* kg_b2 = (const float*)d_in[5];
    const float* bg_w1 = (const float*)d_in[6];
    const float* bg_b1 = (const float*)d_in[7];
    const float* bg_w2 = (const float*)d_in[8];
    const float* bg_b2 = (const float*)d_in[9];
    const float* en_w  = (const float*)d_in[10];
    const float* bn_g  = (const float*)d_in[11];
    const float* bn_b  = (const float*)d_in[12];
    const float* bn_m  = (const float*)d_in[13];
    const float* bn_v  = (const float*)d_in[14];
    float* out = (float*)d_out;

    char* ws = (char*)d_ws;
    float*  pooled = (float*)(ws + 0);                    // 16 KB
    float*  dyn_b  = (float*)(ws + 16384);                // 8 KB
    float*  hk     = (float*)(ws + 24576);                // 4 KB
    float*  hb     = (float*)(ws + 28672);                // 2 KB
    ushort* dynk   = (ushort*)(ws + 32768);               // 4.72 MB [b][kk][o][c]
    ushort* enh    = (ushort*)(ws + 32768 + 4718592);     // 64 MB NHWC bf16

    zero_pooled_kernel<<<16, 256, 0, stream>>>(pooled);
    enhance_kernel<<<dim3(HDIM, B_), 256, 0, stream>>>(ir, vi, en_w, bn_g, bn_b,
                                                       bn_m, bn_v, enh, pooled);
    gen_mlp1_kernel<<<6, 256, 0, stream>>>(pooled, kg_w1, kg_b1, bg_w1, bg_b1, hk, hb);
    gen_dynk_kernel<<<576, 256, 0, stream>>>(kg_w2, kg_b2, hk, hb, bg_w2, bg_b2, dynk, dyn_b);
    dynconv_kernel<<<dim3(WDIM / 16, HDIM / 8, B_), 256, 0, stream>>>(enh, dynk, dyn_b, out);
}